// Round 16
// baseline (234.327 us; speedup 1.0000x reference)
//
#include <hip/hip_runtime.h>
#include <math.h>

#define SEQ 2048
#define NHD 16

typedef float f32x4 __attribute__((ext_vector_type(4), may_alias));
typedef _Float16 h16x8 __attribute__((ext_vector_type(8), may_alias));
typedef _Float16 h16x4 __attribute__((ext_vector_type(4), may_alias));

// async global->LDS, 16B per lane; dst wave-uniform base (+lane*16 in HW)
__device__ __forceinline__ void gl_lds16(const void* g, void* l) {
  __builtin_amdgcn_global_load_lds(
      (const __attribute__((address_space(1))) unsigned int*)g,
      (__attribute__((address_space(3))) unsigned int*)l, 16, 0, 0);
}

// ---------------------------------------------------------------------------
// Fused prepass: blocks [0,1024): transpose W{q,k,v,o} fp32->fp16 [n][k]
//                blocks [1024,7168): convert q,k,v fp32->fp16
// ---------------------------------------------------------------------------
struct PrepArgs {
  const float* W[4];
  _Float16* T[4];
  const float* X[3];
  _Float16* H[3];
};

__global__ __launch_bounds__(256) void prep_k(PrepArgs a) {
  __shared__ float tile[64][65];
  const int blk = blockIdx.x;
  const int t = threadIdx.x;
  if (blk < 1024) {
    const int widx = blk >> 8, tl = blk & 255;
    const int nb = (tl & 15) * 64, kb = (tl >> 4) * 64;
    const float* __restrict__ W = a.W[widx];
    _Float16* __restrict__ T = a.T[widx];
    const int c = t & 63, r0 = t >> 6;
#pragma unroll
    for (int i = 0; i < 16; ++i) {
      const int r = i * 4 + r0;
      tile[r][c] = W[(size_t)(kb + r) * 1024 + nb + c];
    }
    __syncthreads();
#pragma unroll
    for (int i = 0; i < 16; ++i) {
      const int n = i * 4 + r0;
      T[(size_t)(nb + n) * 1024 + kb + c] = (_Float16)tile[c][n];
    }
  } else {
    const int b2 = blk - 1024;
    const int z = b2 >> 11, bx = b2 & 2047;
    const float* __restrict__ X = a.X[z];
    _Float16* __restrict__ H = a.H[z];
    const size_t i = ((size_t)bx * 256 + t) * 8;
    const f32x4 f0 = *(const f32x4*)(X + i);
    const f32x4 f1 = *(const f32x4*)(X + i + 4);
    const float fs[8] = {f0.x, f0.y, f0.z, f0.w, f1.x, f1.y, f1.z, f1.w};
    h16x8 o;
#pragma unroll
    for (int j = 0; j < 8; ++j) o[j] = (_Float16)fs[j];
    *(h16x8*)(H + i) = o;
  }
}

// ---------------------------------------------------------------------------
// fp16 MFMA GEMM: C = A[4096 x 1024] @ Bt^T + bias.
// 256x256 tile, BK=64, 512 thr (8 waves, 2Mx4N), counted-vmcnt pipeline,
// grid 192 (R2/R6-verified).
// z<2 (Q,K): head-split fp16 output. z==2 (V): LDS-transpose + tau
// key'-permute epilogue writes Vt[bh][64][2048] directly.
// ---------------------------------------------------------------------------
struct QKVArgs {
  const _Float16* A[3];
  const _Float16* Bt[3];
  const float* bias[3];
  _Float16* C[3];
};

__global__ __launch_bounds__(512, 2) void gemm_qkv_k(QKVArgs a) {
  __shared__ __align__(16) char smem[131072];  // buf0 [0,64K): A32K,B32K; buf1 [64K,128K)
  const int dblk = blockIdx.x;  // 192 = 3 z * 16 m * 4 n
  const int z = dblk >> 6;
  const int rb = dblk & 63;
  const int m0 = (rb >> 2) * 256;
  const int n0 = (rb & 3) * 256;
  const _Float16* __restrict__ A = a.A[z];
  const _Float16* __restrict__ Bt = a.Bt[z];
  const float* __restrict__ bias = a.bias[z];
  _Float16* __restrict__ C = a.C[z];

  const int t = threadIdx.x;
  const int l = t & 63, w = t >> 6;
  const int quad = l >> 4, l15 = l & 15;
  const int wm = w >> 2, wn = w & 3;  // 2 x 4 wave grid

  const int srow = t >> 3;            // 0..63 within sweep
  const int sslot = (t & 7) ^ (srow & 7);
  size_t goffA[4], goffB[4];
#pragma unroll
  for (int j = 0; j < 4; ++j) {
    goffA[j] = (size_t)(m0 + j * 64 + srow) * 1024 + sslot * 8;
    goffB[j] = (size_t)(n0 + j * 64 + srow) * 1024 + sslot * 8;
  }

  auto stage = [&](int buf, int kt) {
    const int k0 = kt * 64;
    char* base = smem + buf * 65536;
#pragma unroll
    for (int j = 0; j < 4; ++j) {
      gl_lds16(A + goffA[j] + k0, base + j * 8192 + w * 1024);
      gl_lds16(Bt + goffB[j] + k0, base + 32768 + j * 8192 + w * 1024);
    }
  };

  const f32x4 z4 = {0.f, 0.f, 0.f, 0.f};
  f32x4 acc[8][4];
#pragma unroll
  for (int i = 0; i < 8; ++i)
#pragma unroll
    for (int j = 0; j < 4; ++j) acc[i][j] = z4;

  const int xr = l15 & 7;

  stage(0, 0);
  for (int kt = 0; kt < 16; ++kt) {
    const int cur = kt & 1;
    if (kt < 15) {
      stage(cur ^ 1, kt + 1);  // 8 more in flight (16 total)
      asm volatile("s_waitcnt vmcnt(8)" ::: "memory");  // cur's 8 landed
    } else {
      asm volatile("s_waitcnt vmcnt(0)" ::: "memory");
    }
    __builtin_amdgcn_sched_barrier(0);
    __builtin_amdgcn_s_barrier();

    const char* base = smem + cur * 65536;
    h16x8 bf[4][2];
#pragma unroll
    for (int nj = 0; nj < 4; ++nj) {
      const int rowB = wn * 64 + nj * 16 + l15;
#pragma unroll
      for (int h = 0; h < 2; ++h) {
        const int sl = (h * 4 + quad) ^ xr;
        bf[nj][h] = *(const h16x8*)(base + 32768 + rowB * 128 + sl * 16);
      }
    }
#pragma unroll
    for (int mi = 0; mi < 8; ++mi) {
      const int rowA = wm * 128 + mi * 16 + l15;
      const h16x8 af0 = *(const h16x8*)(base + rowA * 128 + ((quad ^ xr) * 16));
      const h16x8 af1 = *(const h16x8*)(base + rowA * 128 + (((4 + quad) ^ xr) * 16));
#pragma unroll
      for (int nj = 0; nj < 4; ++nj) {
        acc[mi][nj] = __builtin_amdgcn_mfma_f32_16x16x32_f16(af0, bf[nj][0], acc[mi][nj], 0, 0, 0);
        acc[mi][nj] = __builtin_amdgcn_mfma_f32_16x16x32_f16(af1, bf[nj][1], acc[mi][nj], 0, 0, 0);
      }
    }
    __builtin_amdgcn_sched_barrier(0);
    __builtin_amdgcn_s_barrier();  // protect cur from next-iter overwrite
  }

  if (z < 2) {
    // Q/K epilogue: head-split fp16 write
#pragma unroll
    for (int mi = 0; mi < 8; ++mi)
#pragma unroll
      for (int nj = 0; nj < 4; ++nj) {
        const int col = n0 + wn * 64 + nj * 16 + l15;
        const float bv = bias[col];
#pragma unroll
        for (int r = 0; r < 4; ++r) {
          const int row = m0 + wm * 128 + mi * 16 + quad * 4 + r;
          const int b = row >> 11, s = row & 2047;
          const int h = col >> 6, d = col & 63;
          C[((size_t)(b * NHD + h) * SEQ + s) * 64 + d] = (_Float16)(acc[mi][nj][r] + bv);
        }
      }
  } else {
    // V epilogue: LDS-transpose + tau key'-permute, write Vt directly.
    _Float16* sh = (_Float16*)smem;  // [256][256] fp16 = 128KB exactly
#pragma unroll
    for (int mi = 0; mi < 8; ++mi)
#pragma unroll
      for (int nj = 0; nj < 4; ++nj) {
        const int col = wn * 64 + nj * 16 + l15;
        const float bv = bias[n0 + col];
#pragma unroll
        for (int r = 0; r < 4; ++r) {
          const int row = wm * 128 + mi * 16 + quad * 4 + r;
          sh[row * 256 + col] = (_Float16)(acc[mi][nj][r] + bv);
        }
      }
    __syncthreads();
    // dest row = (hh,d) pair; each thread writes 128 contiguous keys (16B st)
    const int dr = t >> 1;      // [0,256)
    const int half = t & 1;     // key half
    const int hh = dr >> 6, d = dr & 63;
    const int b = m0 >> 11, sbase = m0 & 2047;
    const int colL = hh * 64 + d;
    const size_t gbase =
        ((size_t)((b * NHD + (n0 >> 6) + hh) * 64 + d)) * SEQ + sbase + half * 128;
#pragma unroll
    for (int m8 = 0; m8 < 16; ++m8) {
      const int qq = half * 128 + m8 * 8;
      h16x8 ov;
#pragma unroll
      for (int j = 0; j < 8; ++j) {
        const int q = qq + j;
        const int g = q >> 6, p = q & 63;
        // inverse tau key'-permute for swapped-QK register-P attn
        const int c = (((p >> 5) << 1) | ((p >> 2) & 1)) * 16 +
                      (((p >> 3) & 3) << 2) + (p & 3);
        ov[j] = sh[(g * 64 + c) * 256 + colL];
      }
      *(h16x8*)(C + gbase + m8 * 8) = ov;
    }
  }
}

// ---------------------------------------------------------------------------
// Output GEMM with fused split-K combine + normalization (2-partial):
//   Cf = relu( [ (Op0+Op1) * inv_l ] @ Wo_t^T + bias ), inv_l = 1/(l0+l1).
// R15/R16: counted-vmcnt raw-barrier loop (3rd application of the proven
// template; __syncthreads' per-iter vmcnt(0) drain serialized the B
// prefetch at 1 block/CU). Queue at vmcnt(6): [stageB(cur)2 oldest,
// loadA(next)4, stageB(next)2] -> waits exactly cur's B. writeA's reg use
// makes the compiler wait the loadA ops. lgkmcnt(0) before the protecting
// barrier publishes the ds_writes (new vs the gl_lds-only kernels).
// ---------------------------------------------------------------------------
__global__ __launch_bounds__(256) void gemm_o_k(
    const _Float16* __restrict__ Op0, const _Float16* __restrict__ Op1,
    const float* __restrict__ Lp, const _Float16* __restrict__ Bt,
    const float* __restrict__ bias, float* __restrict__ Cf) {
  __shared__ char smem[40960];
  float* inv_lds = (float*)(smem + 32768);  // [row_local][head]
  const int rb = blockIdx.x;  // 256 blocks
  const int n0 = ((rb >> 3) & 7) * 128;
  const int m0 = ((((rb >> 6) << 3) | (rb & 7))) * 128;
  const int t = threadIdx.x;
  const int l = t & 63, w = t >> 6;
  const int quad = l >> 4, l15 = l & 15;
  const int wm = w >> 1, wn = w & 1;
  const int arow0 = t >> 2, aq = t & 3;

#pragma unroll
  for (int e = t; e < 2048; e += 256) {
    const int rl = e >> 4, hh = e & 15;
    const int m = m0 + rl;
    const int b = m >> 11, s = m & 2047;
    const size_t li = (size_t)(b * NHD + hh) * 2048 + s;
    inv_lds[e] = 1.f / (Lp[li] + Lp[65536 + li]);
  }
  __syncthreads();  // inv table ready (writeA reads it)

  auto stageB = [&](int buf, int k0) {
#pragma unroll
    for (int it = 0; it < 2; ++it) {
      const int c = it * 4 + w;
      const int rr = c * 16 + l15;
      gl_lds16(Bt + (size_t)(n0 + rr) * 1024 + k0 + quad * 8,
               smem + buf * 8192 + c * 1024);
    }
  };
  auto loadA = [&](int k0, h16x8 (&r0)[2], h16x8 (&r1)[2]) {
#pragma unroll
    for (int it = 0; it < 2; ++it) {
      const size_t off = (size_t)(m0 + it * 64 + arow0) * 1024 + k0 + aq * 8;
      r0[it] = *(const h16x8*)(Op0 + off);
      r1[it] = *(const h16x8*)(Op1 + off);
    }
  };
  auto writeA = [&](int buf, int k0, const h16x8 (&r0)[2], const h16x8 (&r1)[2]) {
    const int head = k0 >> 6;
    h16x8* alds = (h16x8*)(smem + 16384 + buf * 8192);
#pragma unroll
    for (int it = 0; it < 2; ++it) {
      const int row = it * 64 + arow0;
      const int slot = (row >> 4) * 64 + aq * 16 + ((row & 15) ^ (aq * 2));
      const float inv = inv_lds[row * 16 + head];
      h16x8 hv;
#pragma unroll
      for (int j = 0; j < 8; ++j)
        hv[j] = (_Float16)(((float)r0[it][j] + (float)r1[it][j]) * inv);
      alds[slot] = hv;
    }
  };

  const f32x4 z4 = {0.f, 0.f, 0.f, 0.f};
  f32x4 acc[4][4];
#pragma unroll
  for (int i = 0; i < 4; ++i)
#pragma unroll
    for (int j = 0; j < 4; ++j) acc[i][j] = z4;

  h16x8 a0r[2], a1r[2];
  loadA(0, a0r, a1r);
  stageB(0, 0);
  writeA(0, 0, a0r, a1r);
  __syncthreads();  // one-time full drain: B(0) landed, alds(0) visible
  for (int kt = 0; kt < 32; ++kt) {
    const int cur = kt & 1;
    const int nk = (kt + 1) * 32;
    if (kt < 31) {
      loadA(nk, a0r, a1r);      // 4 reg loads: latency hides under MFMA
      stageB(cur ^ 1, nk);      // 2 gl_lds async B prefetch
      asm volatile("s_waitcnt vmcnt(6)" ::: "memory");  // cur's B landed
    } else {
      asm volatile("s_waitcnt vmcnt(0)" ::: "memory");
    }
    __builtin_amdgcn_sched_barrier(0);
    __builtin_amdgcn_s_barrier();  // B(cur) ready on all waves

    const h16x8* blds = (const h16x8*)(smem + cur * 8192);
    const h16x8* alds = (const h16x8*)(smem + 16384 + cur * 8192);
    h16x8 af[4], bf[4];
#pragma unroll
    for (int i = 0; i < 4; ++i) {
      af[i] = alds[(wm * 4 + i) * 64 + quad * 16 + (l15 ^ (quad * 2))];
      bf[i] = blds[(wn * 4 + i) * 64 + l];
    }
#pragma unroll
    for (int i = 0; i < 4; ++i)
#pragma unroll
      for (int j = 0; j < 4; ++j)
        acc[i][j] = __builtin_amdgcn_mfma_f32_16x16x32_f16(af[i], bf[j], acc[i][j], 0, 0, 0);
    if (kt < 31) writeA(cur ^ 1, nk, a0r, a1r);  // write-late into next buf
    __builtin_amdgcn_sched_barrier(0);
    asm volatile("s_waitcnt lgkmcnt(0)" ::: "memory");  // publish ds_writes
    __builtin_amdgcn_s_barrier();  // protect cur from next-iter overwrite
  }
#pragma unroll
  for (int i = 0; i < 4; ++i)
#pragma unroll
    for (int j = 0; j < 4; ++j) {
      const int col = n0 + wn * 64 + j * 16 + l15;
      const float bv = bias[col];
#pragma unroll
      for (int r = 0; r < 4; ++r) {
        const int row = m0 + wm * 64 + i * 16 + quad * 4 + r;
        Cf[(size_t)row * 1024 + col] = fmaxf(acc[i][j][r] + bv, 0.f);
      }
    }
}

// ---------------------------------------------------------------------------
// Flash attention, split-K=2 (grid 1024, 4 blocks/CU). Register-P swapped-QK,
// R6 compute body. R13-verified (52.4us): K+V double-buffered LDS (32KB),
// 2-barrier counted-vmcnt loop: stage(next,4) -> vmcnt(4) -> barrier ->
// compute(cur) -> barrier. No vmcnt(0) drain in the main loop.
// LDS: buf0 K[0,8K) V[8K,16K); buf1 +16K. 4 blocks/CU (128KB).
// ---------------------------------------------------------------------------
__global__ __launch_bounds__(256, 4) void attn_k(
    const _Float16* __restrict__ Qf, const _Float16* __restrict__ Kf,
    const _Float16* __restrict__ Vtp,
    _Float16* __restrict__ Op0, _Float16* __restrict__ Op1,
    float* __restrict__ Lp) {
  __shared__ __align__(16) char smem[32768];
  const int dblk = blockIdx.x;  // 1024 blocks
  const int comb = ((dblk >> 7) << 3) | (dblk & 7);  // (bh,kz) combo, [0,64)
  const int q0 = ((dblk >> 3) & 15) * 128;
  const int bh = comb >> 1;
  const int kz = comb & 1;
  const int t = threadIdx.x;
  const int l = t & 63, w = t >> 6;
  const int quad = l >> 4, l15 = l & 15;
  const int b = bh >> 4, h = bh & 15;

  const _Float16* Kb = Kf + (size_t)bh * SEQ * 64;
  const _Float16* Vtb = Vtp + (size_t)bh * 64 * SEQ;

  h16x8 qf[2][2];
#pragma unroll
  for (int mi = 0; mi < 2; ++mi) {
    const size_t qb = ((size_t)bh * SEQ + q0 + w * 32 + mi * 16 + l15) * 64;
#pragma unroll
    for (int ks = 0; ks < 2; ++ks)
      qf[mi][ks] = *(const h16x8*)&Qf[qb + ks * 32 + quad * 8];
  }
  const _Float16 qs = (_Float16)0.125f;
#pragma unroll
  for (int mi = 0; mi < 2; ++mi)
#pragma unroll
    for (int ks = 0; ks < 2; ++ks) qf[mi][ks] = qf[mi][ks] * qs;

  auto stage = [&](int buf, int k0) {
    char* base = smem + buf * 16384;
#pragma unroll
    for (int it = 0; it < 2; ++it) {
      const int c = it * 4 + w;
      const int kd = (c >> 1) * 16 + l15;
      const int off2 = (c & 1) * 32 + quad * 8;
      gl_lds16(Kb + (size_t)(k0 + kd) * 64 + off2, base + c * 1024);
      gl_lds16(Vtb + (size_t)kd * SEQ + k0 + off2, base + 8192 + c * 1024);
    }
  };

  const f32x4 z4 = {0.f, 0.f, 0.f, 0.f};
  f32x4 oacc[2][4];
  float lsum[2] = {0.f, 0.f};
#pragma unroll
  for (int mi = 0; mi < 2; ++mi)
#pragma unroll
    for (int i = 0; i < 4; ++i) oacc[mi][i] = z4;

  const int kbeg = kz * 1024;
  stage(0, kbeg);  // 4 vm ops in flight
  for (int kt = 0; kt < 16; ++kt) {
    const int cur = kt & 1;
    if (kt < 15) {
      stage(cur ^ 1, kbeg + (kt + 1) * 64);  // +4 -> [cur4, next4]
      asm volatile("s_waitcnt vmcnt(4)" ::: "memory");  // cur's 4 landed
    } else {
      asm volatile("s_waitcnt vmcnt(0)" ::: "memory");
    }
    __builtin_amdgcn_sched_barrier(0);
    __builtin_amdgcn_s_barrier();

    const h16x8* lds8 = (const h16x8*)(smem + cur * 16384);

    // QK + exp phase: per-mi, per-nt K frag loads (short live ranges)
    h16x8 pa[2][2];
#pragma unroll
    for (int mi = 0; mi < 2; ++mi) {
      f32x4 sacc[4];
#pragma unroll
      for (int nt = 0; nt < 4; ++nt) {
        const h16x8 kf0 = lds8[(nt * 2 + 0) * 64 + l];
        const h16x8 kf1 = lds8[(nt * 2 + 1) * 64 + l];
        f32x4 s = z4;
        s = __builtin_amdgcn_mfma_f32_16x16x32_f16(kf0, qf[mi][0], s, 0, 0, 0);
        s = __builtin_amdgcn_mfma_f32_16x16x32_f16(kf1, qf[mi][1], s, 0, 0, 0);
        sacc[nt] = s;
      }
      float ls = 0.f;
#pragma unroll
      for (int r = 0; r < 4; ++r) {
        const _Float16 e0 = (_Float16)__expf(sacc[0][r]);
        const _Float16 e1 = (_Float16)__expf(sacc[1][r]);
        const _Float16 e2 = (_Float16)__expf(sacc[2][r]);
        const _Float16 e3 = (_Float16)__expf(sacc[3][r]);
        pa[mi][0][r] = e0;
        pa[mi][0][4 + r] = e1;
        pa[mi][1][r] = e2;
        pa[mi][1][4 + r] = e3;
        ls += (float)e0 + (float)e1 + (float)e2 + (float)e3;
      }
      lsum[mi] += ls;
    }

    // PV phase: per-nt V frag loads
#pragma unroll
    for (int nt = 0; nt < 4; ++nt) {
      const h16x8 vf0 = lds8[512 + (nt * 2 + 0) * 64 + l];
      const h16x8 vf1 = lds8[512 + (nt * 2 + 1) * 64 + l];
#pragma unroll
      for (int mi = 0; mi < 2; ++mi) {
        oacc[mi][nt] = __builtin_amdgcn_mfma_f32_16x16x32_f16(pa[mi][0], vf0, oacc[mi][nt], 0, 0, 0);
        oacc[mi][nt] = __builtin_amdgcn_mfma_f32_16x16x32_f16(pa[mi][1], vf1, oacc[mi][nt], 0, 0, 0);
      }
    }
    __builtin_amdgcn_sched_barrier(0);
    __builtin_amdgcn_s_barrier();  // protect cur from next-iter overwrite
  }

  _Float16* __restrict__ Op = kz ? Op1 : Op0;
#pragma unroll
  for (int mi = 0; mi < 2; ++mi)
#pragma unroll
    for (int nt = 0; nt < 4; ++nt)
#pragma unroll
      for (int r = 0; r < 4; ++r) {
        const size_t tok = (size_t)b * SEQ + q0 + w * 32 + mi * 16 + quad * 4 + r;
        Op[tok * 1024 + h * 64 + nt * 16 + l15] = (_Float16)oacc[mi][nt][r];
      }
  // l: cross-quad reduce (lanes sharing l15), then store from quad 0
#pragma unroll
  for (int mi = 0; mi < 2; ++mi) {
    float v = lsum[mi];
    v += __shfl_xor(v, 16);
    v += __shfl_xor(v, 32);
    if (quad == 0) {
      const int row = q0 + w * 32 + mi * 16 + l15;
      Lp[(size_t)kz * 65536 + bh * 2048 + row] = v;
    }
  }
}

// ---------------------------------------------------------------------------
extern "C" void kernel_launch(void* const* d_in, const int* in_sizes, int n_in,
                              void* d_out, int out_size, void* d_ws, size_t ws_size,
                              hipStream_t stream) {
  const float* q = (const float*)d_in[0];
  const float* k = (const float*)d_in[1];
  const float* v = (const float*)d_in[2];
  const float* Wq = (const float*)d_in[3];
  const float* bq = (const float*)d_in[4];
  const float* Wk = (const float*)d_in[5];
  const float* bk = (const float*)d_in[6];
  const float* Wv = (const float*)d_in[7];
  const float* bv = (const float*)d_in[8];
  const float* Wo = (const float*)d_in[9];
  const float* bo = (const float*)d_in[10];

  char* W8 = (char*)d_ws;
  const size_t MB = 1024 * 1024;
  auto F = [&](size_t off) { return (_Float16*)(W8 + off); };
  // [0,8M): Wt f16 x4 | [8M,16M): qf (-> Op0) | [16M,24M): kf (-> Op1)
  // [24M,32M): vf | [32M,40M): Qf | [40M,48M): Kf | [56M,64M): Vt
  // [64M,+512K): Lp
  _Float16* wt[4] = {F(0), F(2 * MB), F(4 * MB), F(6 * MB)};
  _Float16* qf = F(8 * MB);
  _Float16* kf = F(16 * MB);
  _Float16* vf = F(24 * MB);
  _Float16* Qf = F(32 * MB);
  _Float16* Kf = F(40 * MB);
  _Float16* Vt = F(56 * MB);
  _Float16* Op0 = F(8 * MB);   // reuses qf (dead after gemm_qkv)
  _Float16* Op1 = F(16 * MB);  // reuses kf (dead after gemm_qkv)
  float* Lp = (float*)(W8 + 64 * MB);

  const dim3 blk(256);

  PrepArgs pa;
  pa.W[0] = Wq; pa.W[1] = Wk; pa.W[2] = Wv; pa.W[3] = Wo;
  pa.T[0] = wt[0]; pa.T[1] = wt[1]; pa.T[2] = wt[2]; pa.T[3] = wt[3];
  pa.X[0] = q; pa.X[1] = k; pa.X[2] = v;
  pa.H[0] = qf; pa.H[1] = kf; pa.H[2] = vf;
  prep_k<<<dim3(7168), blk, 0, stream>>>(pa);

  QKVArgs qa;
  qa.A[0] = qf; qa.A[1] = kf; qa.A[2] = vf;
  qa.Bt[0] = wt[0]; qa.Bt[1] = wt[1]; qa.Bt[2] = wt[2];
  qa.bias[0] = bq; qa.bias[1] = bk; qa.bias[2] = bv;
  qa.C[0] = Qf; qa.C[1] = Kf; qa.C[2] = Vt;  // V written directly as Vt
  gemm_qkv_k<<<dim3(192), dim3(512), 0, stream>>>(qa);

  attn_k<<<dim3(1024), blk, 0, stream>>>(Qf, Kf, Vt, Op0, Op1, Lp);
  gemm_o_k<<<dim3(256), blk, 0, stream>>>(Op0, Op1, Lp, wt[3], bo, (float*)d_out);
}

// Round 17
// 230.193 us; speedup vs baseline: 1.0180x; 1.0180x over previous
//
#include <hip/hip_runtime.h>
#include <math.h>

#define SEQ 2048
#define NHD 16

typedef float f32x4 __attribute__((ext_vector_type(4), may_alias));
typedef _Float16 h16x8 __attribute__((ext_vector_type(8), may_alias));
typedef _Float16 h16x4 __attribute__((ext_vector_type(4), may_alias));

// async global->LDS, 16B per lane; dst wave-uniform base (+lane*16 in HW)
__device__ __forceinline__ void gl_lds16(const void* g, void* l) {
  __builtin_amdgcn_global_load_lds(
      (const __attribute__((address_space(1))) unsigned int*)g,
      (__attribute__((address_space(3))) unsigned int*)l, 16, 0, 0);
}

// ---------------------------------------------------------------------------
// Fused prepass: blocks [0,1024): transpose W{q,k,v,o} fp32->fp16 [n][k]
//                blocks [1024,7168): convert q,k,v fp32->fp16
// ---------------------------------------------------------------------------
struct PrepArgs {
  const float* W[4];
  _Float16* T[4];
  const float* X[3];
  _Float16* H[3];
};

__global__ __launch_bounds__(256) void prep_k(PrepArgs a) {
  __shared__ float tile[64][65];
  const int blk = blockIdx.x;
  const int t = threadIdx.x;
  if (blk < 1024) {
    const int widx = blk >> 8, tl = blk & 255;
    const int nb = (tl & 15) * 64, kb = (tl >> 4) * 64;
    const float* __restrict__ W = a.W[widx];
    _Float16* __restrict__ T = a.T[widx];
    const int c = t & 63, r0 = t >> 6;
#pragma unroll
    for (int i = 0; i < 16; ++i) {
      const int r = i * 4 + r0;
      tile[r][c] = W[(size_t)(kb + r) * 1024 + nb + c];
    }
    __syncthreads();
#pragma unroll
    for (int i = 0; i < 16; ++i) {
      const int n = i * 4 + r0;
      T[(size_t)(nb + n) * 1024 + kb + c] = (_Float16)tile[c][n];
    }
  } else {
    const int b2 = blk - 1024;
    const int z = b2 >> 11, bx = b2 & 2047;
    const float* __restrict__ X = a.X[z];
    _Float16* __restrict__ H = a.H[z];
    const size_t i = ((size_t)bx * 256 + t) * 8;
    const f32x4 f0 = *(const f32x4*)(X + i);
    const f32x4 f1 = *(const f32x4*)(X + i + 4);
    const float fs[8] = {f0.x, f0.y, f0.z, f0.w, f1.x, f1.y, f1.z, f1.w};
    h16x8 o;
#pragma unroll
    for (int j = 0; j < 8; ++j) o[j] = (_Float16)fs[j];
    *(h16x8*)(H + i) = o;
  }
}

// ---------------------------------------------------------------------------
// fp16 MFMA GEMM: C = A[4096 x 1024] @ Bt^T + bias.
// 256x256 tile, BK=64, 512 thr (8 waves, 2Mx4N), counted-vmcnt pipeline,
// grid 192 (R2/R6-verified).
// z<2 (Q,K): head-split fp16 output. z==2 (V): LDS-transpose + tau
// key'-permute epilogue writes Vt[bh][64][2048] directly.
// ---------------------------------------------------------------------------
struct QKVArgs {
  const _Float16* A[3];
  const _Float16* Bt[3];
  const float* bias[3];
  _Float16* C[3];
};

__global__ __launch_bounds__(512, 2) void gemm_qkv_k(QKVArgs a) {
  __shared__ __align__(16) char smem[131072];  // buf0 [0,64K): A32K,B32K; buf1 [64K,128K)
  const int dblk = blockIdx.x;  // 192 = 3 z * 16 m * 4 n
  const int z = dblk >> 6;
  const int rb = dblk & 63;
  const int m0 = (rb >> 2) * 256;
  const int n0 = (rb & 3) * 256;
  const _Float16* __restrict__ A = a.A[z];
  const _Float16* __restrict__ Bt = a.Bt[z];
  const float* __restrict__ bias = a.bias[z];
  _Float16* __restrict__ C = a.C[z];

  const int t = threadIdx.x;
  const int l = t & 63, w = t >> 6;
  const int quad = l >> 4, l15 = l & 15;
  const int wm = w >> 2, wn = w & 3;  // 2 x 4 wave grid

  const int srow = t >> 3;            // 0..63 within sweep
  const int sslot = (t & 7) ^ (srow & 7);
  size_t goffA[4], goffB[4];
#pragma unroll
  for (int j = 0; j < 4; ++j) {
    goffA[j] = (size_t)(m0 + j * 64 + srow) * 1024 + sslot * 8;
    goffB[j] = (size_t)(n0 + j * 64 + srow) * 1024 + sslot * 8;
  }

  auto stage = [&](int buf, int kt) {
    const int k0 = kt * 64;
    char* base = smem + buf * 65536;
#pragma unroll
    for (int j = 0; j < 4; ++j) {
      gl_lds16(A + goffA[j] + k0, base + j * 8192 + w * 1024);
      gl_lds16(Bt + goffB[j] + k0, base + 32768 + j * 8192 + w * 1024);
    }
  };

  const f32x4 z4 = {0.f, 0.f, 0.f, 0.f};
  f32x4 acc[8][4];
#pragma unroll
  for (int i = 0; i < 8; ++i)
#pragma unroll
    for (int j = 0; j < 4; ++j) acc[i][j] = z4;

  const int xr = l15 & 7;

  stage(0, 0);
  for (int kt = 0; kt < 16; ++kt) {
    const int cur = kt & 1;
    if (kt < 15) {
      stage(cur ^ 1, kt + 1);  // 8 more in flight (16 total)
      asm volatile("s_waitcnt vmcnt(8)" ::: "memory");  // cur's 8 landed
    } else {
      asm volatile("s_waitcnt vmcnt(0)" ::: "memory");
    }
    __builtin_amdgcn_sched_barrier(0);
    __builtin_amdgcn_s_barrier();

    const char* base = smem + cur * 65536;
    h16x8 bf[4][2];
#pragma unroll
    for (int nj = 0; nj < 4; ++nj) {
      const int rowB = wn * 64 + nj * 16 + l15;
#pragma unroll
      for (int h = 0; h < 2; ++h) {
        const int sl = (h * 4 + quad) ^ xr;
        bf[nj][h] = *(const h16x8*)(base + 32768 + rowB * 128 + sl * 16);
      }
    }
#pragma unroll
    for (int mi = 0; mi < 8; ++mi) {
      const int rowA = wm * 128 + mi * 16 + l15;
      const h16x8 af0 = *(const h16x8*)(base + rowA * 128 + ((quad ^ xr) * 16));
      const h16x8 af1 = *(const h16x8*)(base + rowA * 128 + (((4 + quad) ^ xr) * 16));
#pragma unroll
      for (int nj = 0; nj < 4; ++nj) {
        acc[mi][nj] = __builtin_amdgcn_mfma_f32_16x16x32_f16(af0, bf[nj][0], acc[mi][nj], 0, 0, 0);
        acc[mi][nj] = __builtin_amdgcn_mfma_f32_16x16x32_f16(af1, bf[nj][1], acc[mi][nj], 0, 0, 0);
      }
    }
    __builtin_amdgcn_sched_barrier(0);
    __builtin_amdgcn_s_barrier();  // protect cur from next-iter overwrite
  }

  if (z < 2) {
    // Q/K epilogue: head-split fp16 write
#pragma unroll
    for (int mi = 0; mi < 8; ++mi)
#pragma unroll
      for (int nj = 0; nj < 4; ++nj) {
        const int col = n0 + wn * 64 + nj * 16 + l15;
        const float bv = bias[col];
#pragma unroll
        for (int r = 0; r < 4; ++r) {
          const int row = m0 + wm * 128 + mi * 16 + quad * 4 + r;
          const int b = row >> 11, s = row & 2047;
          const int h = col >> 6, d = col & 63;
          C[((size_t)(b * NHD + h) * SEQ + s) * 64 + d] = (_Float16)(acc[mi][nj][r] + bv);
        }
      }
  } else {
    // V epilogue: LDS-transpose + tau key'-permute, write Vt directly.
    _Float16* sh = (_Float16*)smem;  // [256][256] fp16 = 128KB exactly
#pragma unroll
    for (int mi = 0; mi < 8; ++mi)
#pragma unroll
      for (int nj = 0; nj < 4; ++nj) {
        const int col = wn * 64 + nj * 16 + l15;
        const float bv = bias[n0 + col];
#pragma unroll
        for (int r = 0; r < 4; ++r) {
          const int row = wm * 128 + mi * 16 + quad * 4 + r;
          sh[row * 256 + col] = (_Float16)(acc[mi][nj][r] + bv);
        }
      }
    __syncthreads();
    // dest row = (hh,d) pair; each thread writes 128 contiguous keys (16B st)
    const int dr = t >> 1;      // [0,256)
    const int half = t & 1;     // key half
    const int hh = dr >> 6, d = dr & 63;
    const int b = m0 >> 11, sbase = m0 & 2047;
    const int colL = hh * 64 + d;
    const size_t gbase =
        ((size_t)((b * NHD + (n0 >> 6) + hh) * 64 + d)) * SEQ + sbase + half * 128;
#pragma unroll
    for (int m8 = 0; m8 < 16; ++m8) {
      const int qq = half * 128 + m8 * 8;
      h16x8 ov;
#pragma unroll
      for (int j = 0; j < 8; ++j) {
        const int q = qq + j;
        const int g = q >> 6, p = q & 63;
        // inverse tau key'-permute for swapped-QK register-P attn
        const int c = (((p >> 5) << 1) | ((p >> 2) & 1)) * 16 +
                      (((p >> 3) & 3) << 2) + (p & 3);
        ov[j] = sh[(g * 64 + c) * 256 + colL];
      }
      *(h16x8*)(C + gbase + m8 * 8) = ov;
    }
  }
}

// ---------------------------------------------------------------------------
// Output GEMM with fused split-K combine + normalization (2-partial):
//   Cf = relu( [ (Op0+Op1) * inv_l ] @ Wo_t^T + bias ), inv_l = 1/(l0+l1).
// R17: reverted to the R14 __syncthreads loop -- the R16 counted-vmcnt
// rewrite was +2.4us (reg-staged A already overlaps; the raw-barrier
// version added lgkmcnt(0)+waitcnt per iter for nothing).
// ---------------------------------------------------------------------------
__global__ __launch_bounds__(256) void gemm_o_k(
    const _Float16* __restrict__ Op0, const _Float16* __restrict__ Op1,
    const float* __restrict__ Lp, const _Float16* __restrict__ Bt,
    const float* __restrict__ bias, float* __restrict__ Cf) {
  __shared__ char smem[40960];
  float* inv_lds = (float*)(smem + 32768);  // [row_local][head]
  const int rb = blockIdx.x;  // 256 blocks
  const int n0 = ((rb >> 3) & 7) * 128;
  const int m0 = ((((rb >> 6) << 3) | (rb & 7))) * 128;
  const int t = threadIdx.x;
  const int l = t & 63, w = t >> 6;
  const int quad = l >> 4, l15 = l & 15;
  const int wm = w >> 1, wn = w & 1;
  const int arow0 = t >> 2, aq = t & 3;

#pragma unroll
  for (int e = t; e < 2048; e += 256) {
    const int rl = e >> 4, hh = e & 15;
    const int m = m0 + rl;
    const int b = m >> 11, s = m & 2047;
    const size_t li = (size_t)(b * NHD + hh) * 2048 + s;
    inv_lds[e] = 1.f / (Lp[li] + Lp[65536 + li]);
  }
  __syncthreads();  // inv table ready (writeA reads it)

  auto stageB = [&](int buf, int k0) {
#pragma unroll
    for (int it = 0; it < 2; ++it) {
      const int c = it * 4 + w;
      const int rr = c * 16 + l15;
      gl_lds16(Bt + (size_t)(n0 + rr) * 1024 + k0 + quad * 8,
               smem + buf * 8192 + c * 1024);
    }
  };
  auto loadA = [&](int k0, h16x8 (&r0)[2], h16x8 (&r1)[2]) {
#pragma unroll
    for (int it = 0; it < 2; ++it) {
      const size_t off = (size_t)(m0 + it * 64 + arow0) * 1024 + k0 + aq * 8;
      r0[it] = *(const h16x8*)(Op0 + off);
      r1[it] = *(const h16x8*)(Op1 + off);
    }
  };
  auto writeA = [&](int buf, int k0, const h16x8 (&r0)[2], const h16x8 (&r1)[2]) {
    const int head = k0 >> 6;
    h16x8* alds = (h16x8*)(smem + 16384 + buf * 8192);
#pragma unroll
    for (int it = 0; it < 2; ++it) {
      const int row = it * 64 + arow0;
      const int slot = (row >> 4) * 64 + aq * 16 + ((row & 15) ^ (aq * 2));
      const float inv = inv_lds[row * 16 + head];
      h16x8 hv;
#pragma unroll
      for (int j = 0; j < 8; ++j)
        hv[j] = (_Float16)(((float)r0[it][j] + (float)r1[it][j]) * inv);
      alds[slot] = hv;
    }
  };

  const f32x4 z4 = {0.f, 0.f, 0.f, 0.f};
  f32x4 acc[4][4];
#pragma unroll
  for (int i = 0; i < 4; ++i)
#pragma unroll
    for (int j = 0; j < 4; ++j) acc[i][j] = z4;

  h16x8 a0r[2], a1r[2];
  loadA(0, a0r, a1r);
  stageB(0, 0);
  writeA(0, 0, a0r, a1r);
  __syncthreads();
  int cur = 0;
  for (int k0 = 0; k0 < 1024; k0 += 32) {
    const int nk = k0 + 32;
    if (nk < 1024) {
      loadA(nk, a0r, a1r);      // issue-early: latency hides under MFMA
      stageB(cur ^ 1, nk);      // async B prefetch
    }
    const h16x8* blds = (const h16x8*)(smem + cur * 8192);
    const h16x8* alds = (const h16x8*)(smem + 16384 + cur * 8192);
    h16x8 af[4], bf[4];
#pragma unroll
    for (int i = 0; i < 4; ++i) {
      af[i] = alds[(wm * 4 + i) * 64 + quad * 16 + (l15 ^ (quad * 2))];
      bf[i] = blds[(wn * 4 + i) * 64 + l];
    }
#pragma unroll
    for (int i = 0; i < 4; ++i)
#pragma unroll
      for (int j = 0; j < 4; ++j)
        acc[i][j] = __builtin_amdgcn_mfma_f32_16x16x32_f16(af[i], bf[j], acc[i][j], 0, 0, 0);
    if (nk < 1024) writeA(cur ^ 1, nk, a0r, a1r);  // write-late into next buf
    __syncthreads();
    cur ^= 1;
  }
#pragma unroll
  for (int i = 0; i < 4; ++i)
#pragma unroll
    for (int j = 0; j < 4; ++j) {
      const int col = n0 + wn * 64 + j * 16 + l15;
      const float bv = bias[col];
#pragma unroll
      for (int r = 0; r < 4; ++r) {
        const int row = m0 + wm * 64 + i * 16 + quad * 4 + r;
        Cf[(size_t)row * 1024 + col] = fmaxf(acc[i][j][r] + bv, 0.f);
      }
    }
}

// ---------------------------------------------------------------------------
// Flash attention, split-K=2 (grid 1024, 4 blocks/CU). Register-P swapped-QK,
// R6 compute body. R13-verified (52.4us): K+V double-buffered LDS (32KB),
// 2-barrier counted-vmcnt loop: stage(next,4) -> vmcnt(4) -> barrier ->
// compute(cur) -> barrier. No vmcnt(0) drain in the main loop.
// LDS: buf0 K[0,8K) V[8K,16K); buf1 +16K. 4 blocks/CU (128KB).
// ---------------------------------------------------------------------------
__global__ __launch_bounds__(256, 4) void attn_k(
    const _Float16* __restrict__ Qf, const _Float16* __restrict__ Kf,
    const _Float16* __restrict__ Vtp,
    _Float16* __restrict__ Op0, _Float16* __restrict__ Op1,
    float* __restrict__ Lp) {
  __shared__ __align__(16) char smem[32768];
  const int dblk = blockIdx.x;  // 1024 blocks
  const int comb = ((dblk >> 7) << 3) | (dblk & 7);  // (bh,kz) combo, [0,64)
  const int q0 = ((dblk >> 3) & 15) * 128;
  const int bh = comb >> 1;
  const int kz = comb & 1;
  const int t = threadIdx.x;
  const int l = t & 63, w = t >> 6;
  const int quad = l >> 4, l15 = l & 15;
  const int b = bh >> 4, h = bh & 15;

  const _Float16* Kb = Kf + (size_t)bh * SEQ * 64;
  const _Float16* Vtb = Vtp + (size_t)bh * 64 * SEQ;

  h16x8 qf[2][2];
#pragma unroll
  for (int mi = 0; mi < 2; ++mi) {
    const size_t qb = ((size_t)bh * SEQ + q0 + w * 32 + mi * 16 + l15) * 64;
#pragma unroll
    for (int ks = 0; ks < 2; ++ks)
      qf[mi][ks] = *(const h16x8*)&Qf[qb + ks * 32 + quad * 8];
  }
  const _Float16 qs = (_Float16)0.125f;
#pragma unroll
  for (int mi = 0; mi < 2; ++mi)
#pragma unroll
    for (int ks = 0; ks < 2; ++ks) qf[mi][ks] = qf[mi][ks] * qs;

  auto stage = [&](int buf, int k0) {
    char* base = smem + buf * 16384;
#pragma unroll
    for (int it = 0; it < 2; ++it) {
      const int c = it * 4 + w;
      const int kd = (c >> 1) * 16 + l15;
      const int off2 = (c & 1) * 32 + quad * 8;
      gl_lds16(Kb + (size_t)(k0 + kd) * 64 + off2, base + c * 1024);
      gl_lds16(Vtb + (size_t)kd * SEQ + k0 + off2, base + 8192 + c * 1024);
    }
  };

  const f32x4 z4 = {0.f, 0.f, 0.f, 0.f};
  f32x4 oacc[2][4];
  float lsum[2] = {0.f, 0.f};
#pragma unroll
  for (int mi = 0; mi < 2; ++mi)
#pragma unroll
    for (int i = 0; i < 4; ++i) oacc[mi][i] = z4;

  const int kbeg = kz * 1024;
  stage(0, kbeg);  // 4 vm ops in flight
  for (int kt = 0; kt < 16; ++kt) {
    const int cur = kt & 1;
    if (kt < 15) {
      stage(cur ^ 1, kbeg + (kt + 1) * 64);  // +4 -> [cur4, next4]
      asm volatile("s_waitcnt vmcnt(4)" ::: "memory");  // cur's 4 landed
    } else {
      asm volatile("s_waitcnt vmcnt(0)" ::: "memory");
    }
    __builtin_amdgcn_sched_barrier(0);
    __builtin_amdgcn_s_barrier();

    const h16x8* lds8 = (const h16x8*)(smem + cur * 16384);

    // QK + exp phase: per-mi, per-nt K frag loads (short live ranges)
    h16x8 pa[2][2];
#pragma unroll
    for (int mi = 0; mi < 2; ++mi) {
      f32x4 sacc[4];
#pragma unroll
      for (int nt = 0; nt < 4; ++nt) {
        const h16x8 kf0 = lds8[(nt * 2 + 0) * 64 + l];
        const h16x8 kf1 = lds8[(nt * 2 + 1) * 64 + l];
        f32x4 s = z4;
        s = __builtin_amdgcn_mfma_f32_16x16x32_f16(kf0, qf[mi][0], s, 0, 0, 0);
        s = __builtin_amdgcn_mfma_f32_16x16x32_f16(kf1, qf[mi][1], s, 0, 0, 0);
        sacc[nt] = s;
      }
      float ls = 0.f;
#pragma unroll
      for (int r = 0; r < 4; ++r) {
        const _Float16 e0 = (_Float16)__expf(sacc[0][r]);
        const _Float16 e1 = (_Float16)__expf(sacc[1][r]);
        const _Float16 e2 = (_Float16)__expf(sacc[2][r]);
        const _Float16 e3 = (_Float16)__expf(sacc[3][r]);
        pa[mi][0][r] = e0;
        pa[mi][0][4 + r] = e1;
        pa[mi][1][r] = e2;
        pa[mi][1][4 + r] = e3;
        ls += (float)e0 + (float)e1 + (float)e2 + (float)e3;
      }
      lsum[mi] += ls;
    }

    // PV phase: per-nt V frag loads
#pragma unroll
    for (int nt = 0; nt < 4; ++nt) {
      const h16x8 vf0 = lds8[512 + (nt * 2 + 0) * 64 + l];
      const h16x8 vf1 = lds8[512 + (nt * 2 + 1) * 64 + l];
#pragma unroll
      for (int mi = 0; mi < 2; ++mi) {
        oacc[mi][nt] = __builtin_amdgcn_mfma_f32_16x16x32_f16(pa[mi][0], vf0, oacc[mi][nt], 0, 0, 0);
        oacc[mi][nt] = __builtin_amdgcn_mfma_f32_16x16x32_f16(pa[mi][1], vf1, oacc[mi][nt], 0, 0, 0);
      }
    }
    __builtin_amdgcn_sched_barrier(0);
    __builtin_amdgcn_s_barrier();  // protect cur from next-iter overwrite
  }

  _Float16* __restrict__ Op = kz ? Op1 : Op0;
#pragma unroll
  for (int mi = 0; mi < 2; ++mi)
#pragma unroll
    for (int nt = 0; nt < 4; ++nt)
#pragma unroll
      for (int r = 0; r < 4; ++r) {
        const size_t tok = (size_t)b * SEQ + q0 + w * 32 + mi * 16 + quad * 4 + r;
        Op[tok * 1024 + h * 64 + nt * 16 + l15] = (_Float16)oacc[mi][nt][r];
      }
  // l: cross-quad reduce (lanes sharing l15), then store from quad 0
#pragma unroll
  for (int mi = 0; mi < 2; ++mi) {
    float v = lsum[mi];
    v += __shfl_xor(v, 16);
    v += __shfl_xor(v, 32);
    if (quad == 0) {
      const int row = q0 + w * 32 + mi * 16 + l15;
      Lp[(size_t)kz * 65536 + bh * 2048 + row] = v;
    }
  }
}

// ---------------------------------------------------------------------------
extern "C" void kernel_launch(void* const* d_in, const int* in_sizes, int n_in,
                              void* d_out, int out_size, void* d_ws, size_t ws_size,
                              hipStream_t stream) {
  const float* q = (const float*)d_in[0];
  const float* k = (const float*)d_in[1];
  const float* v = (const float*)d_in[2];
  const float* Wq = (const float*)d_in[3];
  const float* bq = (const float*)d_in[4];
  const float* Wk = (const float*)d_in[5];
  const float* bk = (const float*)d_in[6];
  const float* Wv = (const float*)d_in[7];
  const float* bv = (const float*)d_in[8];
  const float* Wo = (const float*)d_in[9];
  const float* bo = (const float*)d_in[10];

  char* W8 = (char*)d_ws;
  const size_t MB = 1024 * 1024;
  auto F = [&](size_t off) { return (_Float16*)(W8 + off); };
  // [0,8M): Wt f16 x4 | [8M,16M): qf (-> Op0) | [16M,24M): kf (-> Op1)
  // [24M,32M): vf | [32M,40M): Qf | [40M,48M): Kf | [56M,64M): Vt
  // [64M,+512K): Lp
  _Float16* wt[4] = {F(0), F(2 * MB), F(4 * MB), F(6 * MB)};
  _Float16* qf = F(8 * MB);
  _Float16* kf = F(16 * MB);
  _Float16* vf = F(24 * MB);
  _Float16* Qf = F(32 * MB);
  _Float16* Kf = F(40 * MB);
  _Float16* Vt = F(56 * MB);
  _Float16* Op0 = F(8 * MB);   // reuses qf (dead after gemm_qkv)
  _Float16* Op1 = F(16 * MB);  // reuses kf (dead after gemm_qkv)
  float* Lp = (float*)(W8 + 64 * MB);

  const dim3 blk(256);

  PrepArgs pa;
  pa.W[0] = Wq; pa.W[1] = Wk; pa.W[2] = Wv; pa.W[3] = Wo;
  pa.T[0] = wt[0]; pa.T[1] = wt[1]; pa.T[2] = wt[2]; pa.T[3] = wt[3];
  pa.X[0] = q; pa.X[1] = k; pa.X[2] = v;
  pa.H[0] = qf; pa.H[1] = kf; pa.H[2] = vf;
  prep_k<<<dim3(7168), blk, 0, stream>>>(pa);

  QKVArgs qa;
  qa.A[0] = qf; qa.A[1] = kf; qa.A[2] = vf;
  qa.Bt[0] = wt[0]; qa.Bt[1] = wt[1]; qa.Bt[2] = wt[2];
  qa.bias[0] = bq; qa.bias[1] = bk; qa.bias[2] = bv;
  qa.C[0] = Qf; qa.C[1] = Kf; qa.C[2] = Vt;  // V written directly as Vt
  gemm_qkv_k<<<dim3(192), dim3(512), 0, stream>>>(qa);

  attn_k<<<dim3(1024), blk, 0, stream>>>(Qf, Kf, Vt, Op0, Op1, Lp);
  gemm_o_k<<<dim3(256), blk, 0, stream>>>(Op0, Op1, Lp, wt[3], bo, (float*)d_out);
}